// Round 1
// baseline (42.150 us; speedup 1.0000x reference)
//
#include <hip/hip_runtime.h>
#include <math.h>

using short8  = __attribute__((ext_vector_type(8))) short;
using short4v = __attribute__((ext_vector_type(4))) short;
using float4v = __attribute__((ext_vector_type(4))) float;

#define D_DIM 1024
#define NCLS  40
#define WSTR  1064          // D + C row stride of padded W
#define TM    64            // rows per block
#define KC    64            // K chunk
#define NCHUNK 16           // 1024 / 64
#define APAD  72            // shorts per LDS row (64 + 8 pad -> 144B stride, breaks bank conflict)

__device__ __forceinline__ short f2bf(float f) {
    union { float f; unsigned u; } x; x.f = f;
    unsigned r = (x.u + 0x7fffu + ((x.u >> 16) & 1u)) >> 16;  // RNE
    return (short)r;
}

// ---- Kernel 1: pack W / W_rev main parts (cols 0..1023) to bf16 workspace Wb[80][1024]
__global__ void convert_w_kernel(const float* __restrict__ W, const float* __restrict__ Wr,
                                 short* __restrict__ Wb) {
    int idx = blockIdx.x * 256 + threadIdx.x;   // 0..81919
    int c = idx >> 10;                          // 0..79 (0..39 fwd, 40..79 rev)
    int k = idx & 1023;
    float v = (c < NCLS) ? W[c * WSTR + k] : Wr[(c - NCLS) * WSTR + k];
    Wb[idx] = f2bf(v);
}

// ---- Kernel 2: GEMM (bf16 MFMA) + per-row sequential chain + combine
__global__ __launch_bounds__(256, 3) void bichain_main(
    const float* __restrict__ src, const short* __restrict__ Wb,
    const float* __restrict__ Wf, const float* __restrict__ Wr,
    const float* __restrict__ bf_, const float* __restrict__ br_,
    float* __restrict__ out)
{
    // LDS layout (reused):
    //   phase 1: As[2][64*72] shorts (18432B) | Ws[2][80*72] shorts (23040B)  = 41472B
    //   phase 2: Lg[64][81] floats (20736B)   | Sc[64][80] floats (20480B at +20992)
    __shared__ __align__(16) unsigned char smem[41472];
    short* As = (short*)smem;
    short* Ws = (short*)(smem + 18432);

    const int tid  = threadIdx.x;
    const int lane = tid & 63;
    const int wave = tid >> 6;
    const int row0 = blockIdx.x * TM;

    // staging mapping: 4 threads per row, each loads 4 float4 along K
    const int s_row = tid >> 2;     // 0..63
    const int s_c4  = tid & 3;      // 0..3
    const float* srcRow = src + (long)(row0 + s_row) * D_DIM + s_c4 * 4;

    float4v a_reg[4];
    short8  w_reg[3];
    float4v acc[5];
#pragma unroll
    for (int t = 0; t < 5; ++t)
#pragma unroll
        for (int r = 0; r < 4; ++r) acc[t][r] = 0.f;

    auto load_regs = [&](int ch) {
        const int k0 = ch * KC;
#pragma unroll
        for (int j = 0; j < 4; ++j)
            a_reg[j] = *(const float4v*)(srcRow + k0 + j * 16);
#pragma unroll
        for (int r = 0; r < 3; ++r) {
            int idx = r * 256 + tid;          // 0..639 cover 80 cls x 8 octets
            if (r < 2 || tid < 128) {
                int cls = idx >> 3, oct = idx & 7;
                w_reg[r] = *(const short8*)(Wb + cls * D_DIM + k0 + oct * 8);
            }
        }
    };

    auto write_lds = [&](int buf) {
        short* Ab = As + buf * (TM * APAD);
#pragma unroll
        for (int j = 0; j < 4; ++j) {
            short4v v;
            v.x = f2bf(a_reg[j].x); v.y = f2bf(a_reg[j].y);
            v.z = f2bf(a_reg[j].z); v.w = f2bf(a_reg[j].w);
            *(short4v*)(Ab + s_row * APAD + j * 16 + s_c4 * 4) = v;
        }
        short* Wbuf = Ws + buf * (80 * APAD);
#pragma unroll
        for (int r = 0; r < 3; ++r) {
            int idx = r * 256 + tid;
            if (r < 2 || tid < 128) {
                int cls = idx >> 3, oct = idx & 7;
                *(short8*)(Wbuf + cls * APAD + oct * 8) = w_reg[r];
            }
        }
    };

    const int lrow = lane & 15;
    const int lk8  = (lane >> 4) * 8;

    auto compute = [&](int buf) {
        const short* Ab = As + buf * (TM * APAD) + (wave * 16) * APAD;  // wave's 16 rows
        const short* Wp = Ws + buf * (80 * APAD);
#pragma unroll
        for (int ks = 0; ks < 2; ++ks) {
            short8 af = *(const short8*)(Ab + lrow * APAD + ks * 32 + lk8);
#pragma unroll
            for (int t = 0; t < 5; ++t) {
                short8 bfr = *(const short8*)(Wp + (t * 16 + lrow) * APAD + ks * 32 + lk8);
                acc[t] = __builtin_amdgcn_mfma_f32_16x16x32_bf16(af, bfr, acc[t], 0, 0, 0);
            }
        }
    };

    // ---- K loop, register->LDS double buffered, 1 barrier per chunk
    load_regs(0);
    write_lds(0);
    __syncthreads();
#pragma unroll 1
    for (int ch = 0; ch < NCHUNK; ++ch) {
        const int cur = ch & 1;
        if (ch < NCHUNK - 1) load_regs(ch + 1);   // issue next-chunk global loads early
        compute(cur);
        if (ch < NCHUNK - 1) {
            write_lds(cur ^ 1);
            __syncthreads();
        }
    }
    __syncthreads();   // all LDS reads done before smem reuse

    // ---- logits -> LDS  (C/D layout: col = lane&15, row = (lane>>4)*4 + reg)
    float* Lg = (float*)smem;            // [64][81]
    float* Sc = (float*)(smem + 20992);  // [64][80]
#pragma unroll
    for (int t = 0; t < 5; ++t)
#pragma unroll
        for (int r = 0; r < 4; ++r) {
            int row = wave * 16 + (lane >> 4) * 4 + r;
            int cls = t * 16 + (lane & 15);
            Lg[row * 81 + cls] = acc[t][r];
        }
    __syncthreads();

    // ---- sequential chain, fp32, one thread per (row, direction)
    if (tid < 128) {
        const int row = tid >> 1;
        const int dir = tid & 1;
        const float* Wt = dir ? Wr : Wf;
        const float* bi = dir ? br_ : bf_;
        float s[NCLS];
#pragma unroll
        for (int i = 0; i < NCLS; ++i) {
            float z = Lg[row * 81 + dir * NCLS + i] + bi[i];
#pragma unroll
            for (int j = 0; j < i; ++j)
                z += s[j] * Wt[i * WSTR + D_DIM + j];
            s[i] = 1.f / (1.f + __expf(-z));
            Sc[row * 80 + dir * NCLS + i] = s[i];
        }
    }
    __syncthreads();

    // ---- combine + coalesced write: out[:,c] = 0.5*(fwd[c] + rev[39-c])
    float* outp = out + (long)row0 * NCLS;
    for (int idx = tid; idx < TM * NCLS; idx += 256) {
        int row = idx / NCLS;
        int c   = idx - row * NCLS;
        outp[idx] = 0.5f * (Sc[row * 80 + c] + Sc[row * 80 + NCLS + (NCLS - 1 - c)]);
    }
}

extern "C" void kernel_launch(void* const* d_in, const int* in_sizes, int n_in,
                              void* d_out, int out_size, void* d_ws, size_t ws_size,
                              hipStream_t stream) {
    const float* src = (const float*)d_in[0];
    // d_in[1] = attn_mask, unused by the reference
    const float* W   = (const float*)d_in[2];
    const float* b   = (const float*)d_in[3];
    const float* Wr  = (const float*)d_in[4];
    const float* br  = (const float*)d_in[5];
    float* out = (float*)d_out;
    short* Wb  = (short*)d_ws;   // 80*1024 bf16 = 160KB scratch

    convert_w_kernel<<<320, 256, 0, stream>>>(W, Wr, Wb);
    bichain_main<<<512, 256, 0, stream>>>(src, Wb, W, Wr, b, br, out);
}